// Round 1
// baseline (353.713 us; speedup 1.0000x reference)
//
#include <hip/hip_runtime.h>

// NonLocalBlock: B=8, C=512, N=4096 (64x64), CR=128.
// proj = w_in[384,512] @ x[b,512,4096] -> emb_a/emb_b/g [b,128,4096]
// weights = softmax(emb_a^T emb_b) over keys; y = weights @ g^T; out = x + w_out @ y^T
//
// ws layout (bf16): ab [8][4096][256] (emb_a cols 0..127, emb_b 128..255, token-major)
//                   gC [8][128][4096] (channel-major, for transpose-free PV staging)
//                   yt [8][4096][128] (token-major)

typedef __attribute__((ext_vector_type(8))) short short8;
typedef __attribute__((ext_vector_type(4))) float f32x4;

__device__ inline unsigned short f2bf(float f) {
  union { float f; unsigned u; } v; v.f = f;
  unsigned u = v.u;
  unsigned r = u + 0x7FFFu + ((u >> 16) & 1u);   // RNE
  return (unsigned short)(r >> 16);
}
__device__ inline unsigned pack2(float a, float b) {
  return (unsigned)f2bf(a) | ((unsigned)f2bf(b) << 16);
}

// ---------------- kernel 1: in-projection GEMM (M=384, K=512, N=4096, per batch) ----
__global__ __launch_bounds__(256) void k_proj(const float* __restrict__ x,
                                              const float* __restrict__ w_in,
                                              unsigned short* __restrict__ ab,
                                              unsigned short* __restrict__ gC) {
  __shared__ unsigned short A_lds[128 * 72];   // w_in tile [128 o][64 c + pad8]
  __shared__ unsigned short B_lds[64 * 72];    // x^T tile  [64 n][64 c + pad8]
  const int t = threadIdx.x;
  const int lane = t & 63;
  const int w = t >> 6;
  const int l15 = lane & 15;
  const int quad = lane >> 4;
  const int n0 = blockIdx.x * 64;
  const int o0 = blockIdx.y * 128;
  const int b = blockIdx.z;

  f32x4 acc[2][4];
#pragma unroll
  for (int i = 0; i < 2; i++)
#pragma unroll
    for (int j = 0; j < 4; j++) acc[i][j] = (f32x4)0.f;

  for (int k0 = 0; k0 < 512; k0 += 64) {
    // stage A: w_in[o0..o0+128][k0..k0+64] fp32 -> bf16
#pragma unroll
    for (int i = 0; i < 8; i++) {
      int idx = t + i * 256;
      int row = idx >> 4, v = idx & 15;
      const float4 d = *(const float4*)&w_in[(size_t)(o0 + row) * 512 + k0 + v * 4];
      uint2 p; p.x = pack2(d.x, d.y); p.y = pack2(d.z, d.w);
      *(uint2*)&A_lds[row * 72 + v * 4] = p;
    }
    // stage B with transpose: x[b][k0+c][n0+n] -> B_lds[n][c]
#pragma unroll
    for (int i = 0; i < 4; i++) {
      int idx = t + i * 256;
      int cr = idx >> 4, v = idx & 15;
      const float4 d = *(const float4*)&x[((size_t)(b * 512 + k0 + cr)) * 4096 + n0 + v * 4];
      B_lds[(v * 4 + 0) * 72 + cr] = f2bf(d.x);
      B_lds[(v * 4 + 1) * 72 + cr] = f2bf(d.y);
      B_lds[(v * 4 + 2) * 72 + cr] = f2bf(d.z);
      B_lds[(v * 4 + 3) * 72 + cr] = f2bf(d.w);
    }
    __syncthreads();
#pragma unroll
    for (int kk = 0; kk < 64; kk += 32) {
      short8 a0 = *(const short8*)&A_lds[(w * 32 + l15) * 72 + kk + quad * 8];
      short8 a1 = *(const short8*)&A_lds[(w * 32 + 16 + l15) * 72 + kk + quad * 8];
#pragma unroll
      for (int ns = 0; ns < 4; ns++) {
        short8 bb = *(const short8*)&B_lds[(ns * 16 + l15) * 72 + kk + quad * 8];
        acc[0][ns] = __builtin_amdgcn_mfma_f32_16x16x32_bf16(a0, bb, acc[0][ns], 0, 0, 0);
        acc[1][ns] = __builtin_amdgcn_mfma_f32_16x16x32_bf16(a1, bb, acc[1][ns], 0, 0, 0);
      }
    }
    __syncthreads();
  }
  // epilogue: C/D layout col=lane&15 (=n), row=quad*4+reg (=o); 4 regs = 4 consecutive o
  if (o0 < 256) {
#pragma unroll
    for (int ms = 0; ms < 2; ms++) {
      int o = o0 + w * 32 + ms * 16 + quad * 4;
#pragma unroll
      for (int ns = 0; ns < 4; ns++) {
        int n = n0 + ns * 16 + l15;
        uint2 p;
        p.x = pack2(acc[ms][ns][0], acc[ms][ns][1]);
        p.y = pack2(acc[ms][ns][2], acc[ms][ns][3]);
        *(uint2*)&ab[((size_t)(b * 4096 + n)) * 256 + o] = p;   // token-major
      }
    }
  } else {
#pragma unroll
    for (int ms = 0; ms < 2; ms++) {
      int og = w * 32 + ms * 16 + quad * 4;   // g channel index
#pragma unroll
      for (int ns = 0; ns < 4; ns++) {
        int n = n0 + ns * 16 + l15;
#pragma unroll
        for (int r = 0; r < 4; r++)
          gC[((size_t)(b * 128 + og + r)) * 4096 + n] = f2bf(acc[ms][ns][r]);
      }
    }
  }
}

// ---------------- kernel 2: flash attention, BQ=64 (16 q/wave), BK=64 keys ----------
__global__ __launch_bounds__(256) void k_attn(const unsigned short* __restrict__ ab,
                                              const unsigned short* __restrict__ gC,
                                              unsigned short* __restrict__ yt) {
  __shared__ unsigned short Q_lds[64 * 136];   // [token][128 c + pad8]
  __shared__ unsigned short K_lds[64 * 136];
  __shared__ unsigned short V_lds[128 * 72];   // [c'][64 key + pad8]
  __shared__ unsigned short P_lds[4 * 16 * 72];// per-wave [16 q][64 key + pad8]
  const int t = threadIdx.x;
  const int lane = t & 63;
  const int w = t >> 6;
  const int l15 = lane & 15;
  const int quad = lane >> 4;
  const int q0 = blockIdx.x * 64;
  const int b = blockIdx.y;

  // stage Q once
#pragma unroll
  for (int i = 0; i < 4; i++) {
    int idx = t + i * 256;
    int row = idx >> 4, v = idx & 15;
    *(uint4*)&Q_lds[row * 136 + v * 8] =
        *(const uint4*)&ab[((size_t)(b * 4096 + q0 + row)) * 256 + v * 8];
  }

  f32x4 O[8];
#pragma unroll
  for (int i = 0; i < 8; i++) O[i] = (f32x4)0.f;
  float mcur = -INFINITY, lsum = 0.f;

  for (int kt0 = 0; kt0 < 4096; kt0 += 64) {
    // stage K (emb_b section, token-major)
#pragma unroll
    for (int i = 0; i < 4; i++) {
      int idx = t + i * 256;
      int row = idx >> 4, v = idx & 15;
      *(uint4*)&K_lds[row * 136 + v * 8] =
          *(const uint4*)&ab[((size_t)(b * 4096 + kt0 + row)) * 256 + 128 + v * 8];
    }
    // stage V (gC channel-major -> direct, no transpose)
#pragma unroll
    for (int i = 0; i < 4; i++) {
      int idx = t + i * 256;
      int row = idx >> 3, v = idx & 7;
      *(uint4*)&V_lds[row * 72 + v * 8] =
          *(const uint4*)&gC[((size_t)(b * 128 + row)) * 4096 + kt0 + v * 8];
    }
    __syncthreads();

    // S^T = K · Q^T  -> D[key][q]: lane owns one q col (l15), 4 consecutive keys/reg
    f32x4 accS[4];
#pragma unroll
    for (int i = 0; i < 4; i++) accS[i] = (f32x4)0.f;
#pragma unroll
    for (int ks = 0; ks < 4; ks++) {
      short8 bq = *(const short8*)&Q_lds[(w * 16 + l15) * 136 + ks * 32 + quad * 8];
#pragma unroll
      for (int mt = 0; mt < 4; mt++) {
        short8 ak = *(const short8*)&K_lds[(mt * 16 + l15) * 136 + ks * 32 + quad * 8];
        accS[mt] = __builtin_amdgcn_mfma_f32_16x16x32_bf16(ak, bq, accS[mt], 0, 0, 0);
      }
    }

    // online softmax: stats are per q = l15; reduce across quads only (xor 16, 32)
    float smax = -INFINITY;
#pragma unroll
    for (int mt = 0; mt < 4; mt++)
#pragma unroll
      for (int r = 0; r < 4; r++) smax = fmaxf(smax, accS[mt][r]);
    smax = fmaxf(smax, __shfl_xor(smax, 16));
    smax = fmaxf(smax, __shfl_xor(smax, 32));
    float mnew = fmaxf(mcur, smax);
    float alpha = __expf(mcur - mnew);   // first iter: exp(-inf)=0
    float rsum = 0.f;
#pragma unroll
    for (int mt = 0; mt < 4; mt++) {
#pragma unroll
      for (int r = 0; r < 4; r++) {
        float p = __expf(accS[mt][r] - mnew);
        accS[mt][r] = p;
        rsum += p;
      }
    }
    rsum += __shfl_xor(rsum, 16);
    rsum += __shfl_xor(rsum, 32);
    lsum = lsum * alpha + rsum;
    mcur = mnew;

    // rescale O: O rows are q = quad*4+r; alpha lives at lane q (cols) -> shuffle
#pragma unroll
    for (int r = 0; r < 4; r++) {
      float ar = __shfl(alpha, quad * 4 + r);
#pragma unroll
      for (int ct = 0; ct < 8; ct++) O[ct][r] *= ar;
    }

    // write P^T -> P_lds[q][key]; lane's 4 values = 4 consecutive keys -> one b64 write
#pragma unroll
    for (int mt = 0; mt < 4; mt++) {
      uint2 p;
      p.x = pack2(accS[mt][0], accS[mt][1]);
      p.y = pack2(accS[mt][2], accS[mt][3]);
      *(uint2*)&P_lds[(w * 16 + l15) * 72 + mt * 16 + quad * 4] = p;
    }

    // O[q][c'] += P · V   (A = P_lds [q][key], B = V_lds [c'][key])
#pragma unroll
    for (int ks2 = 0; ks2 < 2; ks2++) {
      short8 ap = *(const short8*)&P_lds[(w * 16 + l15) * 72 + ks2 * 32 + quad * 8];
#pragma unroll
      for (int ct = 0; ct < 8; ct++) {
        short8 bv = *(const short8*)&V_lds[(ct * 16 + l15) * 72 + ks2 * 32 + quad * 8];
        O[ct] = __builtin_amdgcn_mfma_f32_16x16x32_bf16(ap, bv, O[ct], 0, 0, 0);
      }
    }
    __syncthreads();
  }

  // epilogue: y = O / l; O rows q = quad*4+r
  float linv = 1.f / lsum;
#pragma unroll
  for (int r = 0; r < 4; r++) {
    float lr = __shfl(linv, quad * 4 + r);
    int tok = q0 + w * 16 + quad * 4 + r;
#pragma unroll
    for (int ct = 0; ct < 8; ct++)
      yt[((size_t)(b * 4096 + tok)) * 128 + ct * 16 + l15] = f2bf(O[ct][r] * lr);
  }
}

// ---------------- kernel 3: out-projection GEMM (M=512, K=128, N=4096) + residual ---
__global__ __launch_bounds__(256) void k_out(const float* __restrict__ x,
                                             const float* __restrict__ w_out,
                                             const unsigned short* __restrict__ yt,
                                             float* __restrict__ out) {
  __shared__ unsigned short A_lds[128 * 136];  // w_out tile [128 o][128 c + pad8]
  __shared__ unsigned short B_lds[64 * 136];   // y tile [64 n][128 c + pad8]
  const int t = threadIdx.x;
  const int lane = t & 63;
  const int w = t >> 6;
  const int l15 = lane & 15;
  const int quad = lane >> 4;
  const int n0 = blockIdx.x * 64;
  const int o0 = blockIdx.y * 128;
  const int b = blockIdx.z;

#pragma unroll
  for (int i = 0; i < 16; i++) {
    int idx = t + i * 256;
    int row = idx >> 5, v = idx & 31;
    const float4 d = *(const float4*)&w_out[(size_t)(o0 + row) * 128 + v * 4];
    uint2 p; p.x = pack2(d.x, d.y); p.y = pack2(d.z, d.w);
    *(uint2*)&A_lds[row * 136 + v * 4] = p;
  }
#pragma unroll
  for (int i = 0; i < 4; i++) {
    int idx = t + i * 256;
    int row = idx >> 4, v = idx & 15;
    *(uint4*)&B_lds[row * 136 + v * 8] =
        *(const uint4*)&yt[((size_t)(b * 4096 + n0 + row)) * 128 + v * 8];
  }
  __syncthreads();

  f32x4 acc[2][4];
#pragma unroll
  for (int i = 0; i < 2; i++)
#pragma unroll
    for (int j = 0; j < 4; j++) acc[i][j] = (f32x4)0.f;
#pragma unroll
  for (int ks = 0; ks < 4; ks++) {
    short8 a0 = *(const short8*)&A_lds[(w * 32 + l15) * 136 + ks * 32 + quad * 8];
    short8 a1 = *(const short8*)&A_lds[(w * 32 + 16 + l15) * 136 + ks * 32 + quad * 8];
#pragma unroll
    for (int ns = 0; ns < 4; ns++) {
      short8 bb = *(const short8*)&B_lds[(ns * 16 + l15) * 136 + ks * 32 + quad * 8];
      acc[0][ns] = __builtin_amdgcn_mfma_f32_16x16x32_bf16(a0, bb, acc[0][ns], 0, 0, 0);
      acc[1][ns] = __builtin_amdgcn_mfma_f32_16x16x32_bf16(a1, bb, acc[1][ns], 0, 0, 0);
    }
  }
#pragma unroll
  for (int ms = 0; ms < 2; ms++) {
    int o = o0 + w * 32 + ms * 16 + quad * 4;
#pragma unroll
    for (int ns = 0; ns < 4; ns++) {
      int n = n0 + ns * 16 + l15;
#pragma unroll
      for (int r = 0; r < 4; r++) {
        size_t off = ((size_t)(b * 512 + o + r)) * 4096 + n;
        out[off] = x[off] + acc[ms][ns][r];
      }
    }
  }
}

extern "C" void kernel_launch(void* const* d_in, const int* in_sizes, int n_in,
                              void* d_out, int out_size, void* d_ws, size_t ws_size,
                              hipStream_t stream) {
  const float* x = (const float*)d_in[0];
  const float* w_in = (const float*)d_in[1];
  const float* w_out = (const float*)d_in[2];
  float* out = (float*)d_out;

  unsigned short* ab = (unsigned short*)d_ws;                 // 8*4096*256 bf16
  unsigned short* gC = ab + (size_t)8 * 4096 * 256;           // 8*128*4096 bf16
  unsigned short* yt = gC + (size_t)8 * 128 * 4096;           // 8*4096*128 bf16

  k_proj<<<dim3(64, 3, 8), 256, 0, stream>>>(x, w_in, ab, gC);
  k_attn<<<dim3(64, 8), 256, 0, stream>>>(ab, gC, yt);
  k_out<<<dim3(64, 4, 8), 256, 0, stream>>>(x, w_out, yt, out);
}